// Round 2
// baseline (61.854 us; speedup 1.0000x reference)
//
#include <hip/hip_runtime.h>

// VoxelQueryAndGrouping — MI355X (gfx950), round 2
// K1: pad xyz (N,3) -> xyz4 (N,4) in d_ws so candidate gathers are 1 dwordx4.
// K2: one wave per query. Phase A: fused 2x64-lane neighbor scan (125 voxels),
//     two ballots back-to-back (halved latency chain). Phase B: stage the
//     K distinct gathered rows into LDS coalesced, then write (M,C,16) and
//     (M,3,16) outputs with nontemporal dwordx4 stores.

constexpr int ZG = 21;
constexpr int YG = 400;
constexpr int XG = 352;
constexpr int NS = 16;   // NSAMPLE
constexpr int CF = 32;   // feature channels
constexpr float R2 = 64.0f; // RADIUS^2

typedef float v4f __attribute__((ext_vector_type(4)));

__global__ __launch_bounds__(256) void pad_xyz_kernel(
    const float* __restrict__ xyz, float4* __restrict__ xyz4, int N)
{
    const int i = blockIdx.x * 256 + threadIdx.x;
    if (i < N) {
        const float* p = xyz + (size_t)i * 3;
        xyz4[i] = make_float4(p[0], p[1], p[2], 0.0f);
    }
}

template<bool USE4>
__global__ __launch_bounds__(256) void vqg_kernel(
    const int*    __restrict__ new_coords,     // (M,4) [b,z,y,x]
    const float*  __restrict__ xyz,            // (N,3)
    const float4* __restrict__ xyz4,           // (N,4) staged (or null)
    const int*    __restrict__ xyz_batch_cnt,  // (B,)
    const float*  __restrict__ new_xyz,        // (M,3)
    const float*  __restrict__ features,       // (N,CF)
    const int*    __restrict__ v2p,            // (B,ZG,YG,XG)
    float* __restrict__ out_feat,              // (M,CF,NS)
    float* __restrict__ out_xyz,               // (M,3,NS)
    float* __restrict__ out_empty,             // (M,)
    int M)
{
    const int lane = threadIdx.x & 63;
    const int wid  = threadIdx.x >> 6;
    const int m    = blockIdx.x * 4 + wid;
    __shared__ int   sg[4][NS];
    __shared__ float tile[4][NS][33];   // padded stride: conflict-free

    const bool active = (m < M);
    int cnt  = 0;
    int boff = 0;

    if (active) {
        const int4 qc = *reinterpret_cast<const int4*>(new_coords + (size_t)m * 4);
        const int b = qc.x, zc = qc.y, yc = qc.z, xc = qc.w;
        const float qx = new_xyz[m * 3 + 0];
        const float qy = new_xyz[m * 3 + 1];
        const float qz = new_xyz[m * 3 + 2];
        for (int i = 0; i < b; ++i) boff += xyz_batch_cnt[i];
        const int* __restrict__ gb = v2p + (size_t)b * (ZG * YG * XG);

        // --- fused neighbor scan: n0 = lane, n1 = 64 + lane (reference order:
        // dz slowest, dx fastest) ---
        const int n0 = lane;
        const int n1 = 64 + lane;
        int pidx0 = -1, pidx1 = -1;
        {
            const int z = zc + (n0 / 25 - 2);
            const int y = yc + ((n0 / 5) % 5 - 2);
            const int x = xc + (n0 % 5 - 2);
            if ((unsigned)z < (unsigned)ZG && (unsigned)y < (unsigned)YG &&
                (unsigned)x < (unsigned)XG)
                pidx0 = gb[((size_t)z * YG + y) * XG + x];
        }
        if (n1 < 125) {
            const int z = zc + (n1 / 25 - 2);
            const int y = yc + ((n1 / 5) % 5 - 2);
            const int x = xc + (n1 % 5 - 2);
            if ((unsigned)z < (unsigned)ZG && (unsigned)y < (unsigned)YG &&
                (unsigned)x < (unsigned)XG)
                pidx1 = gb[((size_t)z * YG + y) * XG + x];
        }

        // Candidate point loads (independent; issue together).
        float p0x = 0, p0y = 0, p0z = 0, p1x = 0, p1y = 0, p1z = 0;
        if (pidx0 >= 0) {
            if (USE4) {
                const float4 p = xyz4[pidx0];
                p0x = p.x; p0y = p.y; p0z = p.z;
            } else {
                p0x = xyz[(size_t)pidx0 * 3 + 0];
                p0y = xyz[(size_t)pidx0 * 3 + 1];
                p0z = xyz[(size_t)pidx0 * 3 + 2];
            }
        }
        if (pidx1 >= 0) {
            if (USE4) {
                const float4 p = xyz4[pidx1];
                p1x = p.x; p1y = p.y; p1z = p.z;
            } else {
                p1x = xyz[(size_t)pidx1 * 3 + 0];
                p1y = xyz[(size_t)pidx1 * 3 + 1];
                p1z = xyz[(size_t)pidx1 * 3 + 2];
            }
        }

        // Exact-match distance: ((dx*dx + dy*dy) + dz*dz), no FMA contraction.
        bool v0 = false, v1 = false;
        if (pidx0 >= 0) {
            const float dx = p0x - qx, dy = p0y - qy, dz = p0z - qz;
            const float d2 = __fadd_rn(__fadd_rn(__fmul_rn(dx, dx), __fmul_rn(dy, dy)),
                                       __fmul_rn(dz, dz));
            v0 = d2 < R2;
        }
        if (pidx1 >= 0) {
            const float dx = p1x - qx, dy = p1y - qy, dz = p1z - qz;
            const float d2 = __fadd_rn(__fadd_rn(__fmul_rn(dx, dx), __fmul_rn(dy, dy)),
                                       __fmul_rn(dz, dz));
            v1 = d2 < R2;
        }

        const unsigned long long below = (1ull << lane) - 1ull;
        const unsigned long long bal0 = __ballot(v0);
        const unsigned long long bal1 = __ballot(v1);
        const int c0   = (int)__popcll(bal0);
        const int pos0 = (int)__popcll(bal0 & below);
        const int pos1 = c0 + (int)__popcll(bal1 & below);
        if (v0 && pos0 < NS) sg[wid][pos0] = pidx0;
        if (v1 && pos1 < NS) sg[wid][pos1] = pidx1;
        cnt = c0 + (int)__popcll(bal1);
    }
    __syncthreads();

    // Resolve final 16 gather rows (duplicates = slot 0; empty = batch offset).
    if (active && lane < NS) {
        int g;
        if (cnt == 0) {
            g = boff;
        } else {
            const int c = cnt < NS ? cnt : NS;
            g = (lane < c) ? sg[wid][lane] : sg[wid][0];
        }
        sg[wid][lane] = g;
    }
    __syncthreads();

    // Stage the K distinct feature rows into LDS, coalesced (2 rows / wave-load).
    const int K = active ? (cnt > 0 ? (cnt < NS ? cnt : NS) : 1) : 0;
    if (active) {
        const int half = lane >> 5;       // 0,1 -> row parity
        const int c    = lane & 31;       // channel
        for (int r = half; r < K; r += 2) {
            tile[wid][r][c] = features[(size_t)sg[wid][r] * CF + c];
        }
    }
    __syncthreads();

    if (active) {
        // grouped_xyz (M,3,NS): 48 floats, one per lane (few distinct rows ->
        // mostly broadcast loads).
        if (lane < 48) {
            const int s = lane & 15;
            const int d = lane >> 4;
            const int row = sg[wid][s];
            const float val = USE4 ? reinterpret_cast<const float*>(xyz4 + row)[d]
                                   : xyz[(size_t)row * 3 + d];
            __builtin_nontemporal_store(val, out_xyz + (size_t)m * 48 + d * 16 + s);
        }
        if (lane == 0)
            __builtin_nontemporal_store(cnt == 0 ? 1.0f : 0.0f, out_empty + m);

        // grouped_features (M,CF,NS) from LDS: dwordx4 nontemporal stores.
        float* __restrict__ of = out_feat + (size_t)m * (CF * NS);
        #pragma unroll
        for (int k = 0; k < 2; ++k) {
            const int c  = k * 16 + (lane >> 2);   // channel 0..31
            const int s0 = (lane & 3) * 4;         // slot base {0,4,8,12}
            v4f v;
            #pragma unroll
            for (int j = 0; j < 4; ++j) {
                const int s = s0 + j;
                v[j] = tile[wid][s < K ? s : 0][c];
            }
            __builtin_nontemporal_store(
                v, reinterpret_cast<v4f*>(of + k * 256 + (lane << 2)));
        }
    }
}

extern "C" void kernel_launch(void* const* d_in, const int* in_sizes, int n_in,
                              void* d_out, int out_size, void* d_ws, size_t ws_size,
                              hipStream_t stream) {
    const int*   new_coords    = (const int*)d_in[0];
    const float* xyz           = (const float*)d_in[1];
    const int*   xyz_batch_cnt = (const int*)d_in[2];
    const float* new_xyz       = (const float*)d_in[3];
    // d_in[4] = new_xyz_batch_cnt (unused)
    const float* features      = (const float*)d_in[5];
    const int*   v2p           = (const int*)d_in[6];

    const int M = in_sizes[0] / 4;
    const int N = in_sizes[1] / 3;

    float* out_feat  = (float*)d_out;                       // M*CF*NS
    float* out_xyz   = out_feat + (size_t)M * CF * NS;      // M*3*NS
    float* out_empty = out_xyz + (size_t)M * 3 * NS;        // M

    const int blocks = (M + 3) / 4;
    const bool use4 = ws_size >= (size_t)N * sizeof(float4);

    if (use4) {
        float4* xyz4 = (float4*)d_ws;
        pad_xyz_kernel<<<(N + 255) / 256, 256, 0, stream>>>(xyz, xyz4, N);
        vqg_kernel<true><<<blocks, 256, 0, stream>>>(
            new_coords, xyz, xyz4, xyz_batch_cnt, new_xyz, features, v2p,
            out_feat, out_xyz, out_empty, M);
    } else {
        vqg_kernel<false><<<blocks, 256, 0, stream>>>(
            new_coords, xyz, nullptr, xyz_batch_cnt, new_xyz, features, v2p,
            out_feat, out_xyz, out_empty, M);
    }
}

// Round 3
// 61.848 us; speedup vs baseline: 1.0001x; 1.0001x over previous
//
#include <hip/hip_runtime.h>

// VoxelQueryAndGrouping — MI355X (gfx950), round 3
// One 64-lane wave per query; ZERO LDS, ZERO __syncthreads. All wave-internal
// communication via ds_permute (ordered slot scatter) + __shfl (broadcast).
// K1 pads xyz (N,3) -> xyz4 (N,4) so candidate gathers are one dwordx4.

constexpr int ZG = 21;
constexpr int YG = 400;
constexpr int XG = 352;
constexpr int NS = 16;   // NSAMPLE
constexpr int CF = 32;   // feature channels
constexpr float R2 = 64.0f; // RADIUS^2

typedef float v4f __attribute__((ext_vector_type(4)));

__global__ __launch_bounds__(256) void pad_xyz_kernel(
    const float* __restrict__ xyz, float4* __restrict__ xyz4, int N)
{
    const int i = blockIdx.x * 256 + threadIdx.x;
    if (i < N) {
        const float* p = xyz + (size_t)i * 3;
        xyz4[i] = make_float4(p[0], p[1], p[2], 0.0f);
    }
}

__global__ __launch_bounds__(256) void vqg_kernel(
    const int*    __restrict__ new_coords,     // (M,4) [b,z,y,x]
    const float4* __restrict__ xyz4,           // (N,4) staged
    const int*    __restrict__ xyz_batch_cnt,  // (B,)
    const float*  __restrict__ new_xyz,        // (M,3)
    const float*  __restrict__ features,       // (N,CF)
    const int*    __restrict__ v2p,            // (B,ZG,YG,XG)
    float* __restrict__ out_feat,              // (M,CF,NS)
    float* __restrict__ out_xyz,               // (M,3,NS)
    float* __restrict__ out_empty,             // (M,)
    int M)
{
    const int lane = threadIdx.x & 63;
    const int m    = (blockIdx.x * 256 + threadIdx.x) >> 6;  // one wave / query
    if (m >= M) return;   // wave-uniform exit; no barriers anywhere

    const int4 qc = *reinterpret_cast<const int4*>(new_coords + (size_t)m * 4);
    const int b = qc.x, zc = qc.y, yc = qc.z, xc = qc.w;
    const float qx = new_xyz[m * 3 + 0];
    const float qy = new_xyz[m * 3 + 1];
    const float qz = new_xyz[m * 3 + 2];
    int boff = 0;
    for (int i = 0; i < b; ++i) boff += xyz_batch_cnt[i];
    const int* __restrict__ gb = v2p + (size_t)b * (ZG * YG * XG);

    // ---- fused neighbor scan (reference order: dz slowest, dx fastest) ----
    const int n0 = lane;
    const int n1 = 64 + lane;
    int pidx0 = -1, pidx1 = -1;
    {
        const int z = zc + (n0 / 25 - 2);
        const int y = yc + ((n0 / 5) % 5 - 2);
        const int x = xc + (n0 % 5 - 2);
        if ((unsigned)z < (unsigned)ZG && (unsigned)y < (unsigned)YG &&
            (unsigned)x < (unsigned)XG)
            pidx0 = gb[((size_t)z * YG + y) * XG + x];
    }
    if (n1 < 125) {
        const int z = zc + (n1 / 25 - 2);
        const int y = yc + ((n1 / 5) % 5 - 2);
        const int x = xc + (n1 % 5 - 2);
        if ((unsigned)z < (unsigned)ZG && (unsigned)y < (unsigned)YG &&
            (unsigned)x < (unsigned)XG)
            pidx1 = gb[((size_t)z * YG + y) * XG + x];
    }

    // Candidate point loads (independent; exec-masked so only pidx>=0 fetch).
    float p0x = 0, p0y = 0, p0z = 0, p1x = 0, p1y = 0, p1z = 0;
    if (pidx0 >= 0) {
        const float4 p = xyz4[pidx0];
        p0x = p.x; p0y = p.y; p0z = p.z;
    }
    if (pidx1 >= 0) {
        const float4 p = xyz4[pidx1];
        p1x = p.x; p1y = p.y; p1z = p.z;
    }

    // Exact-match distance: ((dx*dx + dy*dy) + dz*dz), no FMA contraction.
    bool v0 = false, v1 = false;
    if (pidx0 >= 0) {
        const float dx = p0x - qx, dy = p0y - qy, dz = p0z - qz;
        v0 = __fadd_rn(__fadd_rn(__fmul_rn(dx, dx), __fmul_rn(dy, dy)),
                       __fmul_rn(dz, dz)) < R2;
    }
    if (pidx1 >= 0) {
        const float dx = p1x - qx, dy = p1y - qy, dz = p1z - qz;
        v1 = __fadd_rn(__fadd_rn(__fmul_rn(dx, dx), __fmul_rn(dy, dy)),
                       __fmul_rn(dz, dz)) < R2;
    }

    const unsigned long long below = (1ull << lane) - 1ull;
    const unsigned long long bal0 = __ballot(v0);
    const unsigned long long bal1 = __ballot(v1);
    const int c0   = (int)__popcll(bal0);
    const int cnt  = c0 + (int)__popcll(bal1);
    const int pos0 = (int)__popcll(bal0 & below);
    const int pos1 = c0 + (int)__popcll(bal1 & below);

    // Register-only ordered slot scatter via ds_permute (push).
    // Valid lanes with pos<16 push pidx to lane `pos`; everyone else pushes
    // into the don't-care lane range [16,48) (addr always < 256: no wrap).
    const int junk  = (16 + (lane & 31)) << 2;
    const int addr0 = (v0 && pos0 < NS) ? (pos0 << 2) : junk;
    const int addr1 = (v1 && pos1 < NS) ? (pos1 << 2) : junk;
    const int perm0 = __builtin_amdgcn_ds_permute(addr0, pidx0);
    const int perm1 = __builtin_amdgcn_ds_permute(addr1, pidx1);

    // Lane s (<16) holds slot s: pass-0 slots are [0,c0), pass-1 fill the rest.
    const int sel   = (lane < c0) ? perm0 : perm1;
    const int first = __shfl(sel, 0);
    const int cnt16 = cnt < NS ? cnt : NS;
    // Final gather row per slot (meaningful for lanes 0..15).
    const int gfin  = (cnt == 0) ? boff : (((lane & 15) < cnt16) ? sel : first);

    // ---- grouped_xyz (M,3,NS): lanes 0..47, one float each ----
    if (lane < 48) {
        const int s = lane & 15;
        const int d = lane >> 4;
        const int row = __shfl(gfin, s);
        const float val = reinterpret_cast<const float*>(xyz4 + row)[d];
        __builtin_nontemporal_store(val, out_xyz + (size_t)m * 48 + d * 16 + s);
    }
    if (lane == 0)
        __builtin_nontemporal_store(cnt == 0 ? 1.0f : 0.0f, out_empty + m);

    // ---- grouped_features (M,CF,NS): direct gather, dwordx4 stores ----
    // Lane covers output floats [lane*4, lane*4+4) within each 256-float half:
    // c = f>>4, s = f&15 -> s0 = (lane&3)*4, c = k*16 + (lane>>2).
    const int s0 = (lane & 3) << 2;
    const int r0 = __shfl(gfin, s0 + 0);
    const int r1 = __shfl(gfin, s0 + 1);
    const int r2 = __shfl(gfin, s0 + 2);
    const int r3 = __shfl(gfin, s0 + 3);
    float* __restrict__ of = out_feat + (size_t)m * (CF * NS);
    #pragma unroll
    for (int k = 0; k < 2; ++k) {
        const int c = k * 16 + (lane >> 2);
        v4f v;
        v[0] = features[(size_t)r0 * CF + c];
        v[1] = features[(size_t)r1 * CF + c];
        v[2] = features[(size_t)r2 * CF + c];
        v[3] = features[(size_t)r3 * CF + c];
        __builtin_nontemporal_store(
            v, reinterpret_cast<v4f*>(of + k * 256 + (lane << 2)));
    }
}

extern "C" void kernel_launch(void* const* d_in, const int* in_sizes, int n_in,
                              void* d_out, int out_size, void* d_ws, size_t ws_size,
                              hipStream_t stream) {
    const int*   new_coords    = (const int*)d_in[0];
    const float* xyz           = (const float*)d_in[1];
    const int*   xyz_batch_cnt = (const int*)d_in[2];
    const float* new_xyz       = (const float*)d_in[3];
    // d_in[4] = new_xyz_batch_cnt (unused)
    const float* features      = (const float*)d_in[5];
    const int*   v2p           = (const int*)d_in[6];

    const int M = in_sizes[0] / 4;
    const int N = in_sizes[1] / 3;

    float* out_feat  = (float*)d_out;                       // M*CF*NS
    float* out_xyz   = out_feat + (size_t)M * CF * NS;      // M*3*NS
    float* out_empty = out_xyz + (size_t)M * 3 * NS;        // M

    float4* xyz4 = (float4*)d_ws;
    pad_xyz_kernel<<<(N + 255) / 256, 256, 0, stream>>>(xyz, xyz4, N);

    const int blocks = (M + 3) / 4;   // 4 waves (queries) per block
    vqg_kernel<<<blocks, 256, 0, stream>>>(
        new_coords, xyz4, xyz_batch_cnt, new_xyz, features, v2p,
        out_feat, out_xyz, out_empty, M);
}